// Round 15
// baseline (263.953 us; speedup 1.0000x reference)
//
#include <hip/hip_runtime.h>
#include <math.h>

#define LL    1024
#define BB    16
#define NN1   2048      // 2*L
#define NNH   51200     // 50*L

using f32x2 = __attribute__((ext_vector_type(2))) float;

// ---- transpose X (16 x 1024) -> XT (1024 x 16), and init z2 = b2 ----
__global__ void k_xt(const float* __restrict__ X, float* __restrict__ XT,
                     const float* __restrict__ b2, float* __restrict__ z2) {
    int id = blockIdx.x * 256 + threadIdx.x;     // 49152 total
    if (id < LL * BB) {
        int n = id >> 4, b = id & 15;
        XT[id] = X[b * LL + n];
    } else {
        int j = id - LL * BB;                    // 0..32767
        z2[j] = b2[j & (NN1 - 1)];
    }
}

// ---------------- stage-1 K-split GEMM partials (R9-proven loop) ----------
// part[s][b][n] = sum_{m in split s} AT[m][b] * W[m][n]
// W read EXACTLY once (16 rows/thread); float2 nt stream; 32 reg accs
// (64 spills: R4/R6; <16 rows duplicates W reads: R5/R11). No LDS/atomics.
// BLK templated: 128-thr blocks = 256 cols/block -> CH can double (halving
// partial traffic) WITHOUT halving block count (R14's mistake).
// __launch_bounds__(BLK,4) = 16 waves/CU for both BLK=128 and BLK=256.
template <int CH, int NCOL, int BLK>
__global__ __launch_bounds__(BLK, 4) void k_gpart(
        const float* __restrict__ AT,    // [KTOT][16]
        const float* __restrict__ W,     // [KTOT][NCOL]
        float* __restrict__ part) {      // [splits][16][NCOL]
    const int t  = threadIdx.x;
    const int n2 = blockIdx.x * (BLK * 2) + t * 2;
    const int s  = blockIdx.y;
    const int m0 = s * CH;

    float2 acc[BB];
#pragma unroll
    for (int r = 0; r < BB; ++r) acc[r] = make_float2(0.f, 0.f);

    const float* wp = W  + (size_t)m0 * NCOL + n2;
    const float* ap = AT + (size_t)m0 * BB;
#pragma unroll 8
    for (int m = 0; m < CH; ++m) {
        const f32x2 w = __builtin_nontemporal_load((const f32x2*)wp); // nt stream
        wp += NCOL;
        const float4 a0 = *(const float4*)(ap + 0);   // uniform addr (SGPR)
        const float4 a1 = *(const float4*)(ap + 4);
        const float4 a2 = *(const float4*)(ap + 8);
        const float4 a3 = *(const float4*)(ap + 12);
        ap += BB;
        acc[ 0].x = fmaf(a0.x, w.x, acc[ 0].x);  acc[ 0].y = fmaf(a0.x, w.y, acc[ 0].y);
        acc[ 1].x = fmaf(a0.y, w.x, acc[ 1].x);  acc[ 1].y = fmaf(a0.y, w.y, acc[ 1].y);
        acc[ 2].x = fmaf(a0.z, w.x, acc[ 2].x);  acc[ 2].y = fmaf(a0.z, w.y, acc[ 2].y);
        acc[ 3].x = fmaf(a0.w, w.x, acc[ 3].x);  acc[ 3].y = fmaf(a0.w, w.y, acc[ 3].y);
        acc[ 4].x = fmaf(a1.x, w.x, acc[ 4].x);  acc[ 4].y = fmaf(a1.x, w.y, acc[ 4].y);
        acc[ 5].x = fmaf(a1.y, w.x, acc[ 5].x);  acc[ 5].y = fmaf(a1.y, w.y, acc[ 5].y);
        acc[ 6].x = fmaf(a1.z, w.x, acc[ 6].x);  acc[ 6].y = fmaf(a1.z, w.y, acc[ 6].y);
        acc[ 7].x = fmaf(a1.w, w.x, acc[ 7].x);  acc[ 7].y = fmaf(a1.w, w.y, acc[ 7].y);
        acc[ 8].x = fmaf(a2.x, w.x, acc[ 8].x);  acc[ 8].y = fmaf(a2.x, w.y, acc[ 8].y);
        acc[ 9].x = fmaf(a2.y, w.x, acc[ 9].x);  acc[ 9].y = fmaf(a2.y, w.y, acc[ 9].y);
        acc[10].x = fmaf(a2.z, w.x, acc[10].x);  acc[10].y = fmaf(a2.z, w.y, acc[10].y);
        acc[11].x = fmaf(a2.w, w.x, acc[11].x);  acc[11].y = fmaf(a2.w, w.y, acc[11].y);
        acc[12].x = fmaf(a3.x, w.x, acc[12].x);  acc[12].y = fmaf(a3.x, w.y, acc[12].y);
        acc[13].x = fmaf(a3.y, w.x, acc[13].x);  acc[13].y = fmaf(a3.y, w.y, acc[13].y);
        acc[14].x = fmaf(a3.z, w.x, acc[14].x);  acc[14].y = fmaf(a3.z, w.y, acc[14].y);
        acc[15].x = fmaf(a3.w, w.x, acc[15].x);  acc[15].y = fmaf(a3.w, w.y, acc[15].y);
    }

    float* pp = part + ((size_t)s * BB) * NCOL + n2;
#pragma unroll
    for (int r = 0; r < BB; ++r)
        *(float2*)(pp + (size_t)r * NCOL) = acc[r];   // plain stores (L3 resident)
}

// ---------------- reduce splits, output TRANSPOSED [N][16] ----------------
// grid (N/256, 4): blockIdx.y = 4-row batch group.
template <bool SIG>
__global__ __launch_bounds__(256) void k_redT(
        const float* __restrict__ part,   // [splits][16][N]
        const float* __restrict__ bias,   // [N] or nullptr
        float* __restrict__ outT,         // [N][16]
        int N, int splits) {
    const int n  = blockIdx.x * 256 + threadIdx.x;
    const int b0 = blockIdx.y * 4;
    float acc[4] = {0.f, 0.f, 0.f, 0.f};
    for (int s = 0; s < splits; ++s) {
        const float* p = part + ((size_t)s * BB + b0) * N + n;
#pragma unroll
        for (int j = 0; j < 4; ++j) acc[j] += p[(size_t)j * N];   // coalesced
    }
    const float bv = bias ? bias[n] : 0.f;
#pragma unroll
    for (int j = 0; j < 4; ++j) {
        float v = acc[j] + bv;
        if (SIG) v = 1.f / (1.f + __expf(-v));
        acc[j] = v;
    }
    *(float4*)(outT + (size_t)n * BB + b0) = make_float4(acc[0], acc[1], acc[2], acc[3]);
}

// ---------------- reduce 128 splits into z2 (pre-init'd with b2) ----------
// grid (128, 4): blockIdx.y = group of 32 splits; one atomicAdd per thread.
__global__ __launch_bounds__(256) void k_redN(
        const float* __restrict__ part,   // [128][16][NN1]
        float* __restrict__ z2) {         // [16][NN1], = b2 on entry
    const int id = blockIdx.x * 256 + threadIdx.x;   // 32768
    const int s0 = blockIdx.y * 32;
    float acc0 = 0.f, acc1 = 0.f;
    for (int s = 0; s < 32; s += 2) {                 // 2-way ILP
        acc0 += part[(size_t)(s0 + s)     * (BB * NN1) + id];
        acc1 += part[(size_t)(s0 + s + 1) * (BB * NN1) + id];
    }
    atomicAdd(&z2[id], acc0 + acc1);                  // 4 atomics/output total
}

// out[b,i] = (1/L) * sum_j ( yr[j]*cos(2*pi*i*j/L) - yi[j]*sin(2*pi*i*j/L) )
// 4-way j-split, 64 i's per block: grid (16,16)=256 blocks -> all 256 CUs.
__global__ __launch_bounds__(256) void k_decode(const float* __restrict__ z2,
                                                float* __restrict__ out) {
    __shared__ float yr[LL], yi[LL];
    __shared__ float partial[3 * 64];
    const int t  = threadIdx.x;
    const int b  = blockIdx.y;
    const int il = t & 63;
    const int i  = blockIdx.x * 64 + il;
    const int jq = t >> 6;                    // 0..3: j-quarter
    for (int j = t; j < LL; j += 256) {
        yr[j] = z2[b * NN1 + j];
        yi[j] = z2[b * NN1 + LL + j];
    }
    __syncthreads();
    const int j0 = jq * 256;
    float acc = 0.f;
    int r = (j0 * i) & (LL - 1);              // (i*j0) mod L, exact
    for (int jj = 0; jj < 256; ++jj) {
        float rev = (float)r * (1.0f / LL);   // revolutions in [0,1)
        float c = __builtin_amdgcn_cosf(rev); // v_cos_f32: cos(2*pi*rev)
        float s = __builtin_amdgcn_sinf(rev); // v_sin_f32: sin(2*pi*rev)
        acc = fmaf(yr[j0 + jj], c, acc);
        acc = fmaf(-yi[j0 + jj], s, acc);
        r = (r + i) & (LL - 1);
    }
    if (jq > 0) partial[(jq - 1) * 64 + il] = acc;
    __syncthreads();
    if (jq == 0)
        out[b * LL + i] = (acc + partial[il] + partial[64 + il] + partial[128 + il])
                          * (1.0f / LL);
}

extern "C" void kernel_launch(void* const* d_in, const int* in_sizes, int n_in,
                              void* d_out, int out_size, void* d_ws, size_t ws_size,
                              hipStream_t stream) {
    const float* X  = (const float*)d_in[0];
    const float* Fc = (const float*)d_in[1];
    const float* W1 = (const float*)d_in[2];
    const float* b1 = (const float*)d_in[3];
    const float* W2 = (const float*)d_in[4];
    const float* b2 = (const float*)d_in[5];
    float* out = (float*)d_out;

    // workspace layout (floats); every element is written before read each call
    float* ws     = (float*)d_ws;
    float* XT     = ws;                       //  1024*16      =    16384
    float* ypredT = XT     + LL * BB;         //  2048*16      =    32768
    float* hT     = ypredT + NN1 * BB;        // 51200*16      =   819200
    float* z2     = hT     + NNH * BB;        //    16*2048    =    32768
    float* parts0 = z2     + BB * NN1;        //  32*16*2048   =  1048576
    float* parts1 = parts0 + 32 * BB * NN1;   //   4*16*51200  =  3276800
    float* parts2 = parts1 + 4 * BB * NNH;    // 128*16*2048   =  4194304
    // total ~9.4M floats = 38 MB

    // X^T + z2 = b2 init
    k_xt<<<dim3((LL * BB + BB * NN1) / 256), 256, 0, stream>>>(X, XT, b2, z2);
    // y_pred^T = (X @ Fc)^T : CH=32, 32 splits, grid (4,32) = 128 blocks  [R13]
    k_gpart<32, NN1, 256><<<dim3(NN1 / 512, 32), 256, 0, stream>>>(XT, Fc, parts0);
    k_redT<false><<<dim3(NN1 / 256, 4), 256, 0, stream>>>(parts0, nullptr, ypredT, NN1, 32);
    // h^T : CH=512, 4 splits, 128-thr blocks, grid (200,4) = 800 blocks (=R13 count)
    k_gpart<512, NNH, 128><<<dim3(NNH / 256, 4), 128, 0, stream>>>(ypredT, W1, parts1);
    k_redT<true><<<dim3(NNH / 256, 4), 256, 0, stream>>>(parts1, b1, hT, NNH, 4);
    // z2 : CH=400, 128 splits, 128-thr blocks, grid (8,128) = 1024 blocks (=R13 count)
    k_gpart<400, NN1, 128><<<dim3(NN1 / 256, 128), 128, 0, stream>>>(hT, W2, parts2);
    k_redN<<<dim3(BB * NN1 / 256, 4), 256, 0, stream>>>(parts2, z2);
    // decode (inverse-DFT form, exact mod-L phase; 4-way j-split, 256 blocks)
    k_decode<<<dim3(LL / 64, BB), 256, 0, stream>>>(z2, out);
}

// Round 16
// 213.103 us; speedup vs baseline: 1.2386x; 1.2386x over previous
//
#include <hip/hip_runtime.h>
#include <math.h>

#define LL    1024
#define BB    16
#define NN1   2048      // 2*L
#define NNH   51200     // 50*L

using f32x2 = __attribute__((ext_vector_type(2))) float;

// ---- transpose X (16 x 1024) -> XT (1024 x 16), and init z2 = b2 ----
__global__ void k_xt(const float* __restrict__ X, float* __restrict__ XT,
                     const float* __restrict__ b2, float* __restrict__ z2) {
    int id = blockIdx.x * 256 + threadIdx.x;     // 49152 total
    if (id < LL * BB) {
        int n = id >> 4, b = id & 15;
        XT[id] = X[b * LL + n];
    } else {
        int j = id - LL * BB;                    // 0..32767
        z2[j] = b2[j & (NN1 - 1)];
    }
}

// ---------------- stage-1 K-split GEMM partials (R9-proven loop) ----------
// part[s][b][n] = sum_{m in split s} AT[m][b] * W[m][n]
// W read EXACTLY once (16 rows/thread); float2 nt stream; 32 reg accs.
// PROVEN CONSTRAINTS (do not revisit):
//  - 64 accs spill (R4 VGPR=52, R6 VGPR=56 even at 128-cap) -> 32 accs max.
//  - <16 rows/thread duplicates W reads (R5, R11) -> all 16 rows/thread.
//  - 256-thr blocks, (256,4), >=800 blocks: ~12 waves/CU. 128-thr blocks at
//    same block count halve in-flight waves (R15, -24%). CH up / blocks down
//    trades occupancy for partial-traffic at a net loss (R14, -19%).
//  => empirical pattern ceiling ~5.2-5.4 TB/s per W stream.
template <int CH, int NCOL>
__global__ __launch_bounds__(256, 4) void k_gpart(
        const float* __restrict__ AT,    // [KTOT][16]
        const float* __restrict__ W,     // [KTOT][NCOL]
        float* __restrict__ part) {      // [splits][16][NCOL]
    const int t  = threadIdx.x;
    const int n2 = blockIdx.x * 512 + t * 2;
    const int s  = blockIdx.y;
    const int m0 = s * CH;

    float2 acc[BB];
#pragma unroll
    for (int r = 0; r < BB; ++r) acc[r] = make_float2(0.f, 0.f);

    const float* wp = W  + (size_t)m0 * NCOL + n2;
    const float* ap = AT + (size_t)m0 * BB;
#pragma unroll 8
    for (int m = 0; m < CH; ++m) {
        const f32x2 w = __builtin_nontemporal_load((const f32x2*)wp); // nt stream
        wp += NCOL;
        const float4 a0 = *(const float4*)(ap + 0);   // uniform addr (SGPR)
        const float4 a1 = *(const float4*)(ap + 4);
        const float4 a2 = *(const float4*)(ap + 8);
        const float4 a3 = *(const float4*)(ap + 12);
        ap += BB;
        acc[ 0].x = fmaf(a0.x, w.x, acc[ 0].x);  acc[ 0].y = fmaf(a0.x, w.y, acc[ 0].y);
        acc[ 1].x = fmaf(a0.y, w.x, acc[ 1].x);  acc[ 1].y = fmaf(a0.y, w.y, acc[ 1].y);
        acc[ 2].x = fmaf(a0.z, w.x, acc[ 2].x);  acc[ 2].y = fmaf(a0.z, w.y, acc[ 2].y);
        acc[ 3].x = fmaf(a0.w, w.x, acc[ 3].x);  acc[ 3].y = fmaf(a0.w, w.y, acc[ 3].y);
        acc[ 4].x = fmaf(a1.x, w.x, acc[ 4].x);  acc[ 4].y = fmaf(a1.x, w.y, acc[ 4].y);
        acc[ 5].x = fmaf(a1.y, w.x, acc[ 5].x);  acc[ 5].y = fmaf(a1.y, w.y, acc[ 5].y);
        acc[ 6].x = fmaf(a1.z, w.x, acc[ 6].x);  acc[ 6].y = fmaf(a1.z, w.y, acc[ 6].y);
        acc[ 7].x = fmaf(a1.w, w.x, acc[ 7].x);  acc[ 7].y = fmaf(a1.w, w.y, acc[ 7].y);
        acc[ 8].x = fmaf(a2.x, w.x, acc[ 8].x);  acc[ 8].y = fmaf(a2.x, w.y, acc[ 8].y);
        acc[ 9].x = fmaf(a2.y, w.x, acc[ 9].x);  acc[ 9].y = fmaf(a2.y, w.y, acc[ 9].y);
        acc[10].x = fmaf(a2.z, w.x, acc[10].x);  acc[10].y = fmaf(a2.z, w.y, acc[10].y);
        acc[11].x = fmaf(a2.w, w.x, acc[11].x);  acc[11].y = fmaf(a2.w, w.y, acc[11].y);
        acc[12].x = fmaf(a3.x, w.x, acc[12].x);  acc[12].y = fmaf(a3.x, w.y, acc[12].y);
        acc[13].x = fmaf(a3.y, w.x, acc[13].x);  acc[13].y = fmaf(a3.y, w.y, acc[13].y);
        acc[14].x = fmaf(a3.z, w.x, acc[14].x);  acc[14].y = fmaf(a3.z, w.y, acc[14].y);
        acc[15].x = fmaf(a3.w, w.x, acc[15].x);  acc[15].y = fmaf(a3.w, w.y, acc[15].y);
    }

    float* pp = part + ((size_t)s * BB) * NCOL + n2;
#pragma unroll
    for (int r = 0; r < BB; ++r)
        *(float2*)(pp + (size_t)r * NCOL) = acc[r];   // plain stores (L3 resident)
}

// ---------------- reduce splits, output TRANSPOSED [N][16] ----------------
// grid (N/256, 4): blockIdx.y = 4-row batch group.
template <bool SIG>
__global__ __launch_bounds__(256) void k_redT(
        const float* __restrict__ part,   // [splits][16][N]
        const float* __restrict__ bias,   // [N] or nullptr
        float* __restrict__ outT,         // [N][16]
        int N, int splits) {
    const int n  = blockIdx.x * 256 + threadIdx.x;
    const int b0 = blockIdx.y * 4;
    float acc[4] = {0.f, 0.f, 0.f, 0.f};
    for (int s = 0; s < splits; ++s) {
        const float* p = part + ((size_t)s * BB + b0) * N + n;
#pragma unroll
        for (int j = 0; j < 4; ++j) acc[j] += p[(size_t)j * N];   // coalesced
    }
    const float bv = bias ? bias[n] : 0.f;
#pragma unroll
    for (int j = 0; j < 4; ++j) {
        float v = acc[j] + bv;
        if (SIG) v = 1.f / (1.f + __expf(-v));
        acc[j] = v;
    }
    *(float4*)(outT + (size_t)n * BB + b0) = make_float4(acc[0], acc[1], acc[2], acc[3]);
}

// ---------------- reduce 256 splits into z2 (pre-init'd with b2) ----------
// grid (128, 4): blockIdx.y = group of 64 splits; one atomicAdd per thread.
__global__ __launch_bounds__(256) void k_redN(
        const float* __restrict__ part,   // [256][16][NN1]
        float* __restrict__ z2) {         // [16][NN1], = b2 on entry
    const int id = blockIdx.x * 256 + threadIdx.x;   // 32768
    const int s0 = blockIdx.y * 64;
    float acc0 = 0.f, acc1 = 0.f;
    for (int s = 0; s < 64; s += 2) {                 // 2-way ILP
        acc0 += part[(size_t)(s0 + s)     * (BB * NN1) + id];
        acc1 += part[(size_t)(s0 + s + 1) * (BB * NN1) + id];
    }
    atomicAdd(&z2[id], acc0 + acc1);                  // 4 atomics/output total
}

// out[b,i] = (1/L) * sum_j ( yr[j]*cos(2*pi*i*j/L) - yi[j]*sin(2*pi*i*j/L) )
// 4-way j-split, 64 i's per block: grid (16,16)=256 blocks -> all 256 CUs.
__global__ __launch_bounds__(256) void k_decode(const float* __restrict__ z2,
                                                float* __restrict__ out) {
    __shared__ float yr[LL], yi[LL];
    __shared__ float partial[3 * 64];
    const int t  = threadIdx.x;
    const int b  = blockIdx.y;
    const int il = t & 63;
    const int i  = blockIdx.x * 64 + il;
    const int jq = t >> 6;                    // 0..3: j-quarter
    for (int j = t; j < LL; j += 256) {
        yr[j] = z2[b * NN1 + j];
        yi[j] = z2[b * NN1 + LL + j];
    }
    __syncthreads();
    const int j0 = jq * 256;
    float acc = 0.f;
    int r = (j0 * i) & (LL - 1);              // (i*j0) mod L, exact
    for (int jj = 0; jj < 256; ++jj) {
        float rev = (float)r * (1.0f / LL);   // revolutions in [0,1)
        float c = __builtin_amdgcn_cosf(rev); // v_cos_f32: cos(2*pi*rev)
        float s = __builtin_amdgcn_sinf(rev); // v_sin_f32: sin(2*pi*rev)
        acc = fmaf(yr[j0 + jj], c, acc);
        acc = fmaf(-yi[j0 + jj], s, acc);
        r = (r + i) & (LL - 1);
    }
    if (jq > 0) partial[(jq - 1) * 64 + il] = acc;
    __syncthreads();
    if (jq == 0)
        out[b * LL + i] = (acc + partial[il] + partial[64 + il] + partial[128 + il])
                          * (1.0f / LL);
}

extern "C" void kernel_launch(void* const* d_in, const int* in_sizes, int n_in,
                              void* d_out, int out_size, void* d_ws, size_t ws_size,
                              hipStream_t stream) {
    const float* X  = (const float*)d_in[0];
    const float* Fc = (const float*)d_in[1];
    const float* W1 = (const float*)d_in[2];
    const float* b1 = (const float*)d_in[3];
    const float* W2 = (const float*)d_in[4];
    const float* b2 = (const float*)d_in[5];
    float* out = (float*)d_out;

    // workspace layout (floats); every element is written before read each call
    float* ws     = (float*)d_ws;
    float* XT     = ws;                       //  1024*16      =    16384
    float* ypredT = XT     + LL * BB;         //  2048*16      =    32768
    float* hT     = ypredT + NN1 * BB;        // 51200*16      =   819200
    float* z2     = hT     + NNH * BB;        //    16*2048    =    32768
    float* parts0 = z2     + BB * NN1;        //  32*16*2048   =  1048576
    float* parts1 = parts0 + 32 * BB * NN1;   //   8*16*51200  =  6553600
    float* parts2 = parts1 + 8 * BB * NNH;    // 256*16*2048   =  8388608
    // total ~16.9M floats = 68 MB

    // X^T + z2 = b2 init
    k_xt<<<dim3((LL * BB + BB * NN1) / 256), 256, 0, stream>>>(X, XT, b2, z2);
    // y_pred^T = (X @ Fc)^T : CH=32, 32 splits, grid (4,32) = 128 blocks
    k_gpart<32, NN1><<<dim3(NN1 / 512, 32), 256, 0, stream>>>(XT, Fc, parts0);
    k_redT<false><<<dim3(NN1 / 256, 4), 256, 0, stream>>>(parts0, nullptr, ypredT, NN1, 32);
    // h^T = sigmoid(y_pred @ W1 + b1)^T : CH=256, 8 splits, grid (100,8) = 800 blocks
    k_gpart<256, NNH><<<dim3(NNH / 512, 8), 256, 0, stream>>>(ypredT, W1, parts1);
    k_redT<true><<<dim3(NNH / 256, 4), 256, 0, stream>>>(parts1, b1, hT, NNH, 8);
    // z2 = h @ W2 + b2 : CH=200, 256 splits, grid (4,256) = 1024 blocks = 4/CU EXACT
    k_gpart<200, NN1><<<dim3(NN1 / 512, 256), 256, 0, stream>>>(hT, W2, parts2);
    k_redN<<<dim3(BB * NN1 / 256, 4), 256, 0, stream>>>(parts2, z2);
    // decode (inverse-DFT form, exact mod-L phase; 4-way j-split, 256 blocks)
    k_decode<<<dim3(LL / 64, BB), 256, 0, stream>>>(z2, out);
}